// Round 1
// baseline (2089.114 us; speedup 1.0000x reference)
//
#include <hip/hip_runtime.h>

#define N_READ   200000
#define N_INTRON 50000
#define N_EDGES  2000000

typedef float f4 __attribute__((ext_vector_type(4)));
typedef float f2 __attribute__((ext_vector_type(2)));

// ---------------- degree count ----------------
__global__ void k_count(const int* __restrict__ src, const int* __restrict__ dst,
                        int* __restrict__ cnt_r, int* __restrict__ cnt_i) {
  int i = blockIdx.x * blockDim.x + threadIdx.x;
  int stride = gridDim.x * blockDim.x;
  for (; i < N_EDGES; i += stride) {
    atomicAdd(&cnt_r[src[i]], 1);
    atomicAdd(&cnt_i[dst[i]], 1);
  }
}

// ---------------- exclusive scan (3 phases) ----------------
__global__ void k_scan1(const int* __restrict__ cnt, int* __restrict__ rp,
                        int* __restrict__ bsum, int n) {
  __shared__ int lds[256];
  int t = threadIdx.x;
  int i = blockIdx.x * 256 + t;
  int v = (i < n) ? cnt[i] : 0;
  lds[t] = v;
  __syncthreads();
  for (int off = 1; off < 256; off <<= 1) {
    int x = (t >= off) ? lds[t - off] : 0;
    __syncthreads();
    lds[t] += x;
    __syncthreads();
  }
  if (i < n) rp[i + 1] = lds[t];
  if (t == 255) bsum[blockIdx.x] = lds[255];
}

__global__ void k_scan2(int* __restrict__ bsum, int nb) {
  __shared__ int lds[1024];
  int t = threadIdx.x;
  int v = (t < nb) ? bsum[t] : 0;
  lds[t] = v;
  __syncthreads();
  for (int off = 1; off < 1024; off <<= 1) {
    int x = (t >= off) ? lds[t - off] : 0;
    __syncthreads();
    lds[t] += x;
    __syncthreads();
  }
  if (t < nb) bsum[t] = lds[t];
}

// finalizes row_ptr, writes cursors (= exclusive start) and rsqrt(max(deg,1))
__global__ void k_scan3(const int* __restrict__ cnt, int* __restrict__ rp,
                        const int* __restrict__ bsum, int* __restrict__ cur,
                        float* __restrict__ rs, int n) {
  int i = blockIdx.x * 256 + threadIdx.x;
  if (i >= n) return;
  int off = (blockIdx.x == 0) ? 0 : bsum[blockIdx.x - 1];
  int inc = rp[i + 1] + off;
  rp[i + 1] = inc;
  int c = cnt[i];
  cur[i] = inc - c;
  rs[i] = rsqrtf((float)(c > 0 ? c : 1));
  if (i == 0) rp[0] = 0;
}

// ---------------- CSR fill (both directions) ----------------
__global__ void k_fill(const int* __restrict__ src, const int* __restrict__ dst,
                       int* __restrict__ cur_r, int* __restrict__ cur_i,
                       int* __restrict__ csr_di_r, int* __restrict__ csr_si_i) {
  int i = blockIdx.x * blockDim.x + threadIdx.x;
  int stride = gridDim.x * blockDim.x;
  for (; i < N_EDGES; i += stride) {
    int s = src[i], d = dst[i];
    int pr = atomicAdd(&cur_r[s], 1);
    csr_di_r[pr] = d;
    int pi = atomicAdd(&cur_i[d], 1);
    csr_si_i[pi] = s;
  }
}

// ---------------- layer-0 input prep: pad 10->16 and pre-scale by rs_read ----------------
__global__ void k_prep_h0(const float* __restrict__ h_read, const float* __restrict__ rs_r,
                          float* __restrict__ h16) {
  int i = blockIdx.x * blockDim.x + threadIdx.x;
  if (i >= N_READ * 16) return;
  int n = i >> 4, c = i & 15;
  h16[i] = (c < 10) ? h_read[n * 10 + c] * rs_r[n] : 0.0f;
}

__global__ void k_prep_W0(const float* __restrict__ W0, float* __restrict__ W0p) {
  int i = blockIdx.x * blockDim.x + threadIdx.x;
  if (i >= 16 * 64) return;
  int k = i >> 6, j = i & 63;
  W0p[i] = (k < 10) ? W0[k * 64 + j] : 0.0f;
}

// ---------------- fused aggregate + GEMM + epilogue layer ----------------
// One block = NT dst nodes. Phase 1: 4 teams of 64 lanes pull-aggregate rows into LDS.
// Phase 2: register-tiled GEMM rows[NT,DIN] @ W[DIN,DOUT], bias+gate+relu(+prescale).
template <int DIN, int DOUT, int NT>
__launch_bounds__(256)
__global__ void k_layer(const float* __restrict__ hsrc, const int* __restrict__ rp,
                        const int* __restrict__ eidx, const float* __restrict__ rs_dst,
                        const float* __restrict__ W, const float* __restrict__ bias,
                        const float* __restrict__ atts, int li,
                        const float* __restrict__ rs_next,  // may be null
                        float* __restrict__ hout, int n_dst) {
  __shared__ float rows[NT * DIN];
  const int tid = threadIdx.x;
  const int nbase = blockIdx.x * NT;
  const int team = tid >> 6, lane = tid & 63;
  constexpr int NPTEAM = NT / 4;

  for (int tl = 0; tl < NPTEAM; ++tl) {
    const int t = team * NPTEAM + tl;
    const int n = nbase + t;
    if constexpr (DIN == 128) {
      f2 acc = {0.f, 0.f};
      if (n < n_dst) {
        const int e0 = rp[n], e1 = rp[n + 1];
        const float rsd = rs_dst[n];
        for (int e = e0; e < e1; ++e) {
          int s = eidx[e];
          acc += *(const f2*)&hsrc[s * 128 + lane * 2];
        }
        acc *= rsd;
      }
      *(f2*)&rows[t * 128 + lane * 2] = acc;
    } else if constexpr (DIN == 64) {
      float acc = 0.f;
      if (n < n_dst) {
        const int e0 = rp[n], e1 = rp[n + 1];
        const float rsd = rs_dst[n];
        for (int e = e0; e < e1; ++e) acc += hsrc[eidx[e] * 64 + lane];
        acc *= rsd;
      }
      rows[t * 64 + lane] = acc;
    } else {  // DIN == 16: 4 edge-slots x 16 cols per wave
      const int slot = lane >> 4, col = lane & 15;
      float acc = 0.f;
      int e0 = 0, e1 = 0;
      float rsd = 0.f;
      if (n < n_dst) { e0 = rp[n]; e1 = rp[n + 1]; rsd = rs_dst[n]; }
      for (int e = e0 + slot; e < e1; e += 4) acc += hsrc[eidx[e] * 16 + col];
      acc += __shfl_xor(acc, 16);
      acc += __shfl_xor(acc, 32);
      if (slot == 0) rows[t * 16 + col] = acc * rsd;
    }
  }
  __syncthreads();

  // GEMM: thread computes NPT nodes x 4 cols
  constexpr int JG = DOUT / 4;
  constexpr int NG = 256 / JG;
  constexpr int NPT = NT / NG;
  const int jg = tid % JG, ng = tid / JG;
  const int j0 = jg * 4, nb0 = ng * NPT;

  f4 acc[NPT];
#pragma unroll
  for (int p = 0; p < NPT; ++p) acc[p] = (f4){0.f, 0.f, 0.f, 0.f};

#pragma unroll 2
  for (int k = 0; k < DIN; k += 4) {
    f4 w[4];
#pragma unroll
    for (int u = 0; u < 4; ++u) w[u] = *(const f4*)&W[(k + u) * DOUT + j0];
#pragma unroll
    for (int p = 0; p < NPT; ++p) {
      f4 r = *(const f4*)&rows[(nb0 + p) * DIN + k];
#pragma unroll
      for (int u = 0; u < 4; ++u) acc[p] += r[u] * w[u];
    }
  }

  const float a = atts[li];
  const float gate = 1.0f / (1.0f + __expf(-a));
  const f4 b4 = *(const f4*)&bias[j0];
#pragma unroll
  for (int p = 0; p < NPT; ++p) {
    const int n = nbase + nb0 + p;
    if (n < n_dst) {
      f4 v = (acc[p] + b4) * gate;
#pragma unroll
      for (int c = 0; c < 4; ++c) v[c] = fmaxf(v[c], 0.f);
      if (rs_next) v *= rs_next[n];
      *(f4*)&hout[n * DOUT + j0] = v;
    }
  }
}

// ---------------- final fc: [N_READ,128] @ [128,2] + b ----------------
__launch_bounds__(128)
__global__ void k_fc(const float* __restrict__ hR, const float* __restrict__ fc_w,
                     const float* __restrict__ fc_b, float* __restrict__ out) {
  __shared__ float lds[64 * 129];
  const int base = blockIdx.x * 64;
  const int tid = threadIdx.x;
  for (int it = 0; it < 64; ++it) {
    int idx = it * 128 + tid;
    int r = idx >> 7, c = idx & 127;
    int n = base + r;
    lds[r * 129 + c] = (n < N_READ) ? hR[n * 128 + c] : 0.f;
  }
  __syncthreads();
  const int nl = tid >> 1, c = tid & 1;
  const int n = base + nl;
  if (n < N_READ) {
    float acc = fc_b[c];
#pragma unroll 8
    for (int k = 0; k < 128; ++k) acc += lds[nl * 129 + k] * fc_w[k * 2 + c];
    out[n * 2 + c] = acc;
  }
}

extern "C" void kernel_launch(void* const* d_in, const int* in_sizes, int n_in,
                              void* d_out, int out_size, void* d_ws, size_t ws_size,
                              hipStream_t stream) {
  const float* h_read = (const float*)d_in[0];
  const int* esrc = (const int*)d_in[1];
  const int* edst = (const int*)d_in[2];
  const float* W0 = (const float*)d_in[3];
  const float* b0 = (const float*)d_in[4];
  const float* W1 = (const float*)d_in[5];
  const float* b1 = (const float*)d_in[6];
  const float* W2 = (const float*)d_in[7];
  const float* b2 = (const float*)d_in[8];
  const float* W3 = (const float*)d_in[9];
  const float* b3 = (const float*)d_in[10];
  const float* W4 = (const float*)d_in[11];
  const float* b4 = (const float*)d_in[12];
  const float* W5 = (const float*)d_in[13];
  const float* b5 = (const float*)d_in[14];
  const float* atts = (const float*)d_in[15];
  const float* fcw = (const float*)d_in[16];
  const float* fcb = (const float*)d_in[17];
  float* out = (float*)d_out;

  char* w = (char*)d_ws;
  size_t off = 0;
  auto alloc = [&](size_t elems) -> void* {
    void* p = w + off;
    off += ((elems + 3) & ~(size_t)3) * 4;  // 16B-align every array
    return p;
  };
  int* cnt_r = (int*)alloc(N_READ);
  int* cnt_i = (int*)alloc(N_INTRON);        // contiguous with cnt_r for one memset
  int* rp_r = (int*)alloc(N_READ + 1);
  int* rp_i = (int*)alloc(N_INTRON + 1);
  int* cur_r = (int*)alloc(N_READ);
  int* cur_i = (int*)alloc(N_INTRON);
  int* bsum = (int*)alloc(1024);
  float* rs_r = (float*)alloc(N_READ);
  float* rs_i = (float*)alloc(N_INTRON);
  int* csr_di_r = (int*)alloc(N_EDGES);      // dst idx, grouped by src (read-dst layers)
  int* csr_si_i = (int*)alloc(N_EDGES);      // src idx, grouped by dst (intron-dst layers)
  float* W0p = (float*)alloc(16 * 64);
  float* hR = (float*)alloc((size_t)N_READ * 128);
  float* hI = (float*)alloc((size_t)N_INTRON * 128);
  float* h16 = hR;  // alias: h16 (L0 source) is dead before hR is first written (L1)

  // --- graph preprocessing (per launch; deterministic work) ---
  hipMemsetAsync(cnt_r, 0, (size_t)(N_READ + N_INTRON) * sizeof(int), stream);
  k_count<<<2048, 256, 0, stream>>>(esrc, edst, cnt_r, cnt_i);

  const int nbR = (N_READ + 255) / 256;    // 782
  const int nbI = (N_INTRON + 255) / 256;  // 196
  k_scan1<<<nbR, 256, 0, stream>>>(cnt_r, rp_r, bsum, N_READ);
  k_scan2<<<1, 1024, 0, stream>>>(bsum, nbR);
  k_scan3<<<nbR, 256, 0, stream>>>(cnt_r, rp_r, bsum, cur_r, rs_r, N_READ);
  k_scan1<<<nbI, 256, 0, stream>>>(cnt_i, rp_i, bsum, N_INTRON);
  k_scan2<<<1, 1024, 0, stream>>>(bsum, nbI);
  k_scan3<<<nbI, 256, 0, stream>>>(cnt_i, rp_i, bsum, cur_i, rs_i, N_INTRON);
  k_fill<<<2048, 256, 0, stream>>>(esrc, edst, cur_r, cur_i, csr_di_r, csr_si_i);

  k_prep_h0<<<(N_READ * 16 + 255) / 256, 256, 0, stream>>>(h_read, rs_r, h16);
  k_prep_W0<<<4, 256, 0, stream>>>(W0, W0p);

  // --- 6 fused layers ---
  const int gI = (N_INTRON + 31) / 32;  // 1563
  const int gR = (N_READ + 31) / 32;    // 6250
  // L0: read->intron, 16(pad of 10)->64, prescale output by rs_i for L1
  k_layer<16, 64, 32><<<gI, 256, 0, stream>>>(h16, rp_i, csr_si_i, rs_i, W0p, b0, atts, 0, rs_i, hI, N_INTRON);
  // L1: intron->read, 64->128, prescale by rs_r for L2
  k_layer<64, 128, 32><<<gR, 256, 0, stream>>>(hI, rp_r, csr_di_r, rs_r, W1, b1, atts, 1, rs_r, hR, N_READ);
  // L2: read->intron, 128->128
  k_layer<128, 128, 32><<<gI, 256, 0, stream>>>(hR, rp_i, csr_si_i, rs_i, W2, b2, atts, 2, rs_i, hI, N_INTRON);
  // L3: intron->read
  k_layer<128, 128, 32><<<gR, 256, 0, stream>>>(hI, rp_r, csr_di_r, rs_r, W3, b3, atts, 3, rs_r, hR, N_READ);
  // L4: read->intron
  k_layer<128, 128, 32><<<gI, 256, 0, stream>>>(hR, rp_i, csr_si_i, rs_i, W4, b4, atts, 4, rs_i, hI, N_INTRON);
  // L5: intron->read, NO prescale (hR consumed raw by fc)
  k_layer<128, 128, 32><<<gR, 256, 0, stream>>>(hI, rp_r, csr_di_r, rs_r, W5, b5, atts, 5, nullptr, hR, N_READ);

  // --- final projection ---
  k_fc<<<(N_READ + 63) / 64, 128, 0, stream>>>(hR, fcw, fcb, out);
}

// Round 2
// 1304.874 us; speedup vs baseline: 1.6010x; 1.6010x over previous
//
#include <hip/hip_runtime.h>

#define N_READ   200000
#define N_INTRON 50000
#define N_EDGES  2000000

typedef float f4 __attribute__((ext_vector_type(4)));
typedef float f2 __attribute__((ext_vector_type(2)));
typedef int   i4 __attribute__((ext_vector_type(4)));

// ---------------- degree count + per-edge rank (rank = atomic return) ----------------
__global__ void k_count(const i4* __restrict__ src4, const i4* __restrict__ dst4,
                        int* __restrict__ cnt_r, int* __restrict__ cnt_i,
                        i4* __restrict__ rank_r4, i4* __restrict__ rank_i4) {
  int i = blockIdx.x * blockDim.x + threadIdx.x;
  if (i >= N_EDGES / 4) return;
  i4 s = src4[i], d = dst4[i];
  i4 rr, ri;
  rr.x = atomicAdd(&cnt_r[s.x], 1); rr.y = atomicAdd(&cnt_r[s.y], 1);
  rr.z = atomicAdd(&cnt_r[s.z], 1); rr.w = atomicAdd(&cnt_r[s.w], 1);
  ri.x = atomicAdd(&cnt_i[d.x], 1); ri.y = atomicAdd(&cnt_i[d.y], 1);
  ri.z = atomicAdd(&cnt_i[d.z], 1); ri.w = atomicAdd(&cnt_i[d.w], 1);
  rank_r4[i] = rr;
  rank_i4[i] = ri;
}

// ---------------- exclusive scan (3 phases) ----------------
__global__ void k_scan1(const int* __restrict__ cnt, int* __restrict__ rp,
                        int* __restrict__ bsum, int n) {
  __shared__ int lds[256];
  int t = threadIdx.x;
  int i = blockIdx.x * 256 + t;
  int v = (i < n) ? cnt[i] : 0;
  lds[t] = v;
  __syncthreads();
  for (int off = 1; off < 256; off <<= 1) {
    int x = (t >= off) ? lds[t - off] : 0;
    __syncthreads();
    lds[t] += x;
    __syncthreads();
  }
  if (i < n) rp[i + 1] = lds[t];
  if (t == 255) bsum[blockIdx.x] = lds[255];
}

__global__ void k_scan2(int* __restrict__ bsum, int nb) {
  __shared__ int lds[1024];
  int t = threadIdx.x;
  int v = (t < nb) ? bsum[t] : 0;
  lds[t] = v;
  __syncthreads();
  for (int off = 1; off < 1024; off <<= 1) {
    int x = (t >= off) ? lds[t - off] : 0;
    __syncthreads();
    lds[t] += x;
    __syncthreads();
  }
  if (t < nb) bsum[t] = lds[t];
}

__global__ void k_scan3(const int* __restrict__ cnt, int* __restrict__ rp,
                        const int* __restrict__ bsum, float* __restrict__ rs, int n) {
  int i = blockIdx.x * 256 + threadIdx.x;
  if (i >= n) return;
  int off = (blockIdx.x == 0) ? 0 : bsum[blockIdx.x - 1];
  rp[i + 1] += off;
  int c = cnt[i];
  rs[i] = rsqrtf((float)(c > 0 ? c : 1));
  if (i == 0) rp[0] = 0;
}

// ---------------- atomic-free CSR fill: slot = rp[node] + rank[edge] ----------------
__global__ void k_fill(const i4* __restrict__ src4, const i4* __restrict__ dst4,
                       const i4* __restrict__ rank_r4, const i4* __restrict__ rank_i4,
                       const int* __restrict__ rp_r, const int* __restrict__ rp_i,
                       int* __restrict__ csr_di_r, int* __restrict__ csr_si_i) {
  int i = blockIdx.x * blockDim.x + threadIdx.x;
  if (i >= N_EDGES / 4) return;
  i4 s = src4[i], d = dst4[i], rr = rank_r4[i], ri = rank_i4[i];
  csr_di_r[rp_r[s.x] + rr.x] = d.x;
  csr_di_r[rp_r[s.y] + rr.y] = d.y;
  csr_di_r[rp_r[s.z] + rr.z] = d.z;
  csr_di_r[rp_r[s.w] + rr.w] = d.w;
  csr_si_i[rp_i[d.x] + ri.x] = s.x;
  csr_si_i[rp_i[d.y] + ri.y] = s.y;
  csr_si_i[rp_i[d.z] + ri.z] = s.z;
  csr_si_i[rp_i[d.w] + ri.w] = s.w;
}

// ---------------- layer-0 input prep: pad 10->16 and pre-scale by rs_read ----------------
__global__ void k_prep_h0(const float* __restrict__ h_read, const float* __restrict__ rs_r,
                          float* __restrict__ h16) {
  int i = blockIdx.x * blockDim.x + threadIdx.x;
  if (i >= N_READ * 16) return;
  int n = i >> 4, c = i & 15;
  h16[i] = (c < 10) ? h_read[n * 10 + c] * rs_r[n] : 0.0f;
}

__global__ void k_prep_W0(const float* __restrict__ W0, float* __restrict__ W0p) {
  int i = blockIdx.x * blockDim.x + threadIdx.x;
  if (i >= 16 * 64) return;
  int k = i >> 6, j = i & 63;
  W0p[i] = (k < 10) ? W0[k * 64 + j] : 0.0f;
}

// ---------------- fused aggregate + GEMM + epilogue layer ----------------
// Phase 1: sub-wave groups pull-aggregate node rows into LDS (x4-unrolled edge loop
//          -> 4 gather requests in flight per group).
// Phase 2: register-tiled GEMM rows[NT,DIN] @ W[DIN,DOUT]; padded LDS stride (+4 floats)
//          and interleaved node mapping (node = ng + p*NG) -> conflict-free ds_read_b128.
// FC=true (L5): keep the output tile in LDS and apply the 128->2 projection in-block.
template <int DIN, int DOUT, bool FC>
__launch_bounds__(256)
__global__ void k_layer(const float* __restrict__ hsrc, const int* __restrict__ rp,
                        const int* __restrict__ eidx, const float* __restrict__ rs_dst,
                        const float* __restrict__ W, const float* __restrict__ bias,
                        const float* __restrict__ atts, int li,
                        const float* __restrict__ rs_next,  // may be null
                        float* __restrict__ hout,
                        const float* __restrict__ fcw, const float* __restrict__ fcb,
                        float* __restrict__ fcout, int n_dst) {
  constexpr int NT = 32;
  constexpr int RSTR = DIN + 4;  // padded LDS row stride (floats)
  __shared__ float rows[NT * RSTR];
  const int tid = threadIdx.x;
  const int nbase = blockIdx.x * NT;
  const int team = tid >> 6, lane = tid & 63;

  if constexpr (DIN == 128) {
    const int sub = lane >> 5, l32 = lane & 31;
    for (int tl = 0; tl < 4; ++tl) {
      const int t = team * 8 + tl * 2 + sub;
      const int n = nbase + t;
      f4 a0 = {0.f, 0.f, 0.f, 0.f}, a1 = a0, a2 = a0, a3 = a0;
      if (n < n_dst) {
        const int e0 = rp[n], e1 = rp[n + 1];
        int e = e0;
        for (; e + 4 <= e1; e += 4) {
          int s0 = eidx[e], s1 = eidx[e + 1], s2 = eidx[e + 2], s3 = eidx[e + 3];
          a0 += *(const f4*)&hsrc[(size_t)s0 * 128 + l32 * 4];
          a1 += *(const f4*)&hsrc[(size_t)s1 * 128 + l32 * 4];
          a2 += *(const f4*)&hsrc[(size_t)s2 * 128 + l32 * 4];
          a3 += *(const f4*)&hsrc[(size_t)s3 * 128 + l32 * 4];
        }
        for (; e < e1; ++e) a0 += *(const f4*)&hsrc[(size_t)eidx[e] * 128 + l32 * 4];
        a0 = (a0 + a1) + (a2 + a3);
        a0 *= rs_dst[n];
      }
      *(f4*)&rows[t * RSTR + l32 * 4] = a0;
    }
  } else if constexpr (DIN == 64) {
    const int sub = lane >> 4, l16 = lane & 15;
    for (int tl = 0; tl < 2; ++tl) {
      const int t = team * 8 + tl * 4 + sub;
      const int n = nbase + t;
      f4 a0 = {0.f, 0.f, 0.f, 0.f}, a1 = a0, a2 = a0, a3 = a0;
      if (n < n_dst) {
        const int e0 = rp[n], e1 = rp[n + 1];
        int e = e0;
        for (; e + 4 <= e1; e += 4) {
          int s0 = eidx[e], s1 = eidx[e + 1], s2 = eidx[e + 2], s3 = eidx[e + 3];
          a0 += *(const f4*)&hsrc[(size_t)s0 * 64 + l16 * 4];
          a1 += *(const f4*)&hsrc[(size_t)s1 * 64 + l16 * 4];
          a2 += *(const f4*)&hsrc[(size_t)s2 * 64 + l16 * 4];
          a3 += *(const f4*)&hsrc[(size_t)s3 * 64 + l16 * 4];
        }
        for (; e < e1; ++e) a0 += *(const f4*)&hsrc[(size_t)eidx[e] * 64 + l16 * 4];
        a0 = (a0 + a1) + (a2 + a3);
        a0 *= rs_dst[n];
      }
      *(f4*)&rows[t * RSTR + l16 * 4] = a0;
    }
  } else {  // DIN == 16
    const int sub = lane >> 3, l8 = lane & 7;
    const int t = team * 8 + sub;
    const int n = nbase + t;
    f2 a0 = {0.f, 0.f}, a1 = a0, a2 = a0, a3 = a0;
    if (n < n_dst) {
      const int e0 = rp[n], e1 = rp[n + 1];
      int e = e0;
      for (; e + 4 <= e1; e += 4) {
        int s0 = eidx[e], s1 = eidx[e + 1], s2 = eidx[e + 2], s3 = eidx[e + 3];
        a0 += *(const f2*)&hsrc[(size_t)s0 * 16 + l8 * 2];
        a1 += *(const f2*)&hsrc[(size_t)s1 * 16 + l8 * 2];
        a2 += *(const f2*)&hsrc[(size_t)s2 * 16 + l8 * 2];
        a3 += *(const f2*)&hsrc[(size_t)s3 * 16 + l8 * 2];
      }
      for (; e < e1; ++e) a0 += *(const f2*)&hsrc[(size_t)eidx[e] * 16 + l8 * 2];
      a0 = (a0 + a1) + (a2 + a3);
      a0 *= rs_dst[n];
    }
    *(f2*)&rows[t * RSTR + l8 * 2] = a0;
  }
  __syncthreads();

  // GEMM: thread computes NPT nodes x 4 cols; nodes interleaved by NG
  constexpr int JG = DOUT / 4;
  constexpr int NG = 256 / JG;
  constexpr int NPT = NT / NG;
  const int jg = tid % JG, ng = tid / JG;
  const int j0 = jg * 4;

  f4 acc[NPT];
#pragma unroll
  for (int p = 0; p < NPT; ++p) acc[p] = (f4){0.f, 0.f, 0.f, 0.f};

#pragma unroll 2
  for (int k = 0; k < DIN; k += 4) {
    f4 w[4];
#pragma unroll
    for (int u = 0; u < 4; ++u) w[u] = *(const f4*)&W[(k + u) * DOUT + j0];
#pragma unroll
    for (int p = 0; p < NPT; ++p) {
      f4 r = *(const f4*)&rows[(ng + p * NG) * RSTR + k];
#pragma unroll
      for (int u = 0; u < 4; ++u) acc[p] += r[u] * w[u];
    }
  }

  const float a = atts[li];
  const float gate = 1.0f / (1.0f + __expf(-a));
  const f4 b4 = *(const f4*)&bias[j0];

  if constexpr (!FC) {
#pragma unroll
    for (int p = 0; p < NPT; ++p) {
      const int nl = ng + p * NG;
      const int n = nbase + nl;
      if (n < n_dst) {
        f4 v = (acc[p] + b4) * gate;
#pragma unroll
        for (int c = 0; c < 4; ++c) v[c] = fmaxf(v[c], 0.f);
        if (rs_next) v *= rs_next[n];
        *(f4*)&hout[(size_t)n * DOUT + j0] = v;
      }
    }
  } else {
    __syncthreads();  // everyone done reading rows before we overwrite it
#pragma unroll
    for (int p = 0; p < NPT; ++p) {
      const int nl = ng + p * NG;
      f4 v = (acc[p] + b4) * gate;
#pragma unroll
      for (int c = 0; c < 4; ++c) v[c] = fmaxf(v[c], 0.f);
      *(f4*)&rows[nl * RSTR + j0] = v;
    }
    __syncthreads();
    // fc: 256 threads = 32 nodes x 2 cols x 4 partial-sums
    const int nl = tid >> 3, c = (tid >> 2) & 1, part = tid & 3;
    float s = 0.f;
    const int k0 = part * 32;
#pragma unroll 8
    for (int k = k0; k < k0 + 32; ++k) s += rows[nl * RSTR + k] * fcw[k * 2 + c];
    s += __shfl_xor(s, 1);
    s += __shfl_xor(s, 2);
    const int n = nbase + nl;
    if (part == 0 && n < n_dst) fcout[n * 2 + c] = s + fcb[c];
  }
}

extern "C" void kernel_launch(void* const* d_in, const int* in_sizes, int n_in,
                              void* d_out, int out_size, void* d_ws, size_t ws_size,
                              hipStream_t stream) {
  const float* h_read = (const float*)d_in[0];
  const int* esrc = (const int*)d_in[1];
  const int* edst = (const int*)d_in[2];
  const float* W0 = (const float*)d_in[3];
  const float* b0 = (const float*)d_in[4];
  const float* W1 = (const float*)d_in[5];
  const float* b1 = (const float*)d_in[6];
  const float* W2 = (const float*)d_in[7];
  const float* b2 = (const float*)d_in[8];
  const float* W3 = (const float*)d_in[9];
  const float* b3 = (const float*)d_in[10];
  const float* W4 = (const float*)d_in[11];
  const float* b4 = (const float*)d_in[12];
  const float* W5 = (const float*)d_in[13];
  const float* b5 = (const float*)d_in[14];
  const float* atts = (const float*)d_in[15];
  const float* fcw = (const float*)d_in[16];
  const float* fcb = (const float*)d_in[17];
  float* out = (float*)d_out;

  char* w = (char*)d_ws;
  size_t off = 0;
  auto alloc = [&](size_t elems) -> void* {
    void* p = w + off;
    off += ((elems + 3) & ~(size_t)3) * 4;  // 16B-align every array
    return p;
  };
  int* cnt_r = (int*)alloc(N_READ);
  int* cnt_i = (int*)alloc(N_INTRON);  // contiguous with cnt_r for one memset
  int* rp_r = (int*)alloc(N_READ + 1);
  int* rp_i = (int*)alloc(N_INTRON + 1);
  int* bsum = (int*)alloc(1024);
  float* rs_r = (float*)alloc(N_READ);
  float* rs_i = (float*)alloc(N_INTRON);
  int* csr_di_r = (int*)alloc(N_EDGES);  // dst idx, grouped by src (read-dst layers)
  int* csr_si_i = (int*)alloc(N_EDGES);  // src idx, grouped by dst (intron-dst layers)
  float* W0p = (float*)alloc(16 * 64);
  float* hR = (float*)alloc((size_t)N_READ * 128);
  float* hI = (float*)alloc((size_t)N_INTRON * 128);
  // Time-multiplexed aliases inside hR (dead until L1 writes it):
  //   rank_r/rank_i live count->fill; h16 lives prep_h0->L0.
  int* rank_r = (int*)hR;
  int* rank_i = rank_r + N_EDGES;
  float* h16 = (float*)hR;

  // --- graph preprocessing (per launch; deterministic work) ---
  hipMemsetAsync(cnt_r, 0, (size_t)(N_READ + N_INTRON) * sizeof(int), stream);
  const int gE4 = (N_EDGES / 4 + 255) / 256;  // 1954
  k_count<<<gE4, 256, 0, stream>>>((const i4*)esrc, (const i4*)edst, cnt_r, cnt_i,
                                   (i4*)rank_r, (i4*)rank_i);

  const int nbR = (N_READ + 255) / 256;    // 782
  const int nbI = (N_INTRON + 255) / 256;  // 196
  k_scan1<<<nbR, 256, 0, stream>>>(cnt_r, rp_r, bsum, N_READ);
  k_scan2<<<1, 1024, 0, stream>>>(bsum, nbR);
  k_scan3<<<nbR, 256, 0, stream>>>(cnt_r, rp_r, bsum, rs_r, N_READ);
  k_scan1<<<nbI, 256, 0, stream>>>(cnt_i, rp_i, bsum, N_INTRON);
  k_scan2<<<1, 1024, 0, stream>>>(bsum, nbI);
  k_scan3<<<nbI, 256, 0, stream>>>(cnt_i, rp_i, bsum, rs_i, N_INTRON);
  k_fill<<<gE4, 256, 0, stream>>>((const i4*)esrc, (const i4*)edst,
                                  (const i4*)rank_r, (const i4*)rank_i,
                                  rp_r, rp_i, csr_di_r, csr_si_i);

  k_prep_h0<<<(N_READ * 16 + 255) / 256, 256, 0, stream>>>(h_read, rs_r, h16);
  k_prep_W0<<<4, 256, 0, stream>>>(W0, W0p);

  // --- 6 fused layers ---
  const int gI = (N_INTRON + 31) / 32;  // 1563
  const int gR = (N_READ + 31) / 32;    // 6250
  k_layer<16, 64, false><<<gI, 256, 0, stream>>>(h16, rp_i, csr_si_i, rs_i, W0p, b0, atts, 0,
                                                 rs_i, hI, nullptr, nullptr, nullptr, N_INTRON);
  k_layer<64, 128, false><<<gR, 256, 0, stream>>>(hI, rp_r, csr_di_r, rs_r, W1, b1, atts, 1,
                                                  rs_r, hR, nullptr, nullptr, nullptr, N_READ);
  k_layer<128, 128, false><<<gI, 256, 0, stream>>>(hR, rp_i, csr_si_i, rs_i, W2, b2, atts, 2,
                                                   rs_i, hI, nullptr, nullptr, nullptr, N_INTRON);
  k_layer<128, 128, false><<<gR, 256, 0, stream>>>(hI, rp_r, csr_di_r, rs_r, W3, b3, atts, 3,
                                                   rs_r, hR, nullptr, nullptr, nullptr, N_READ);
  k_layer<128, 128, false><<<gI, 256, 0, stream>>>(hR, rp_i, csr_si_i, rs_i, W4, b4, atts, 4,
                                                   rs_i, hI, nullptr, nullptr, nullptr, N_INTRON);
  // L5: intron->read, fc fused in-block (no hR store, no separate fc kernel)
  k_layer<128, 128, true><<<gR, 256, 0, stream>>>(hI, rp_r, csr_di_r, rs_r, W5, b5, atts, 5,
                                                  nullptr, hR, fcw, fcb, out, N_READ);
}